// Round 6
// baseline (274.106 us; speedup 1.0000x reference)
//
#include <hip/hip_runtime.h>
#include <math.h>

// GMM log-prob, S=1024 D=256 K=8 d=32. Target = dtype-faithful f32 numpy ref.
// cov is replicated BIT-EXACTLY in f32 per numpy's SSE3-baseline einsum
// (mul-round + 4-lane reversed add chains + hadd tree + f32 ridge) -- this is
// what makes the test pass; do not perturb that ordering.
// Precompute: one 32-lane half-wave per (d,k) pair, row-per-lane in REGISTERS,
// cross-lane via __shfl width=32. No LDS, no barriers. f64 Cholesky +
// triangular inverse. Outputs f32 Linv/b/c for the f32 heavy kernel.
// Heavy kernel: f32 z = Linv*y - b, maha, online logsumexp.
// ws layout (f32): Linv [2048*1024] | b [2048*32] | c [2048]  (~8.5 MB)

__global__ __launch_bounds__(256) void gmm_precompute(
    const float* __restrict__ mix,      // [256,8]
    const float* __restrict__ mean_p,   // [256,8,32]
    const float* __restrict__ cov_p,    // [256,8,32,32]
    const float* __restrict__ ds_stds,  // [256,32]
    float* __restrict__ LinvOut,        // [2048,32,32]
    float* __restrict__ bOut,           // [2048,32]
    float* __restrict__ cOut)           // [2048]
{
    const int tid  = threadIdx.x;
    const int sub  = tid >> 5;                 // 0..7 half-wave in block
    const int r    = tid & 31;                 // row owned by this lane
    const int pair = blockIdx.x * 8 + sub;     // 0..2047
    const int dd   = pair >> 3;
    const int k    = pair & 7;

    // ---- load W row r (32 f32, registers) ----
    float w[32];
    {
        const float4* wp = (const float4*)(cov_p + (size_t)pair * 1024 + r * 32);
        #pragma unroll
        for (int q = 0; q < 8; ++q) {
            const float4 v = wp[q];
            w[4*q+0] = v.x; w[4*q+1] = v.y; w[4*q+2] = v.z; w[4*q+3] = v.w;
        }
    }

    // ---- cov row r in f32 (exact SSE3-emulated order), upconvert to f64 ----
    double A[32];
    #pragma unroll
    for (int c = 0; c < 32; ++c) {
        float p[32];
        #pragma unroll
        for (int j = 0; j < 32; ++j)
            p[j] = __fmul_rn(w[j], __shfl(w[j], c, 32));
        float acc[4];
        #pragma unroll
        for (int l = 0; l < 4; ++l) {
            float t1 = p[12+l];
            t1 = __fadd_rn(p[8+l], t1);
            t1 = __fadd_rn(p[4+l], t1);
            t1 = __fadd_rn(p[0+l], t1);
            float t2 = __fadd_rn(p[28+l], t1);
            t2 = __fadd_rn(p[24+l], t2);
            t2 = __fadd_rn(p[20+l], t2);
            acc[l] = __fadd_rn(p[16+l], t2);
        }
        float s = __fadd_rn(__fadd_rn(acc[0], acc[1]), __fadd_rn(acc[2], acc[3]));
        if (c == r) s = __fadd_rn(s, 1.0e-5f);
        A[c] = (double)s;
    }

    // ---- Cholesky (f64), in place in A; lane r holds row r of L ----
    double hld = 0.0;   // sum log diag, computed uniformly on all lanes
    #pragma unroll
    for (int c = 0; c < 32; ++c) {
        const double dv   = __shfl(A[c], c, 32);   // updated C[c][c]
        const double dcc  = sqrt(dv);
        hld += log(dcc);
        const double invd = 1.0 / dcc;
        const double lrc  = A[c] * invd;
        A[c] = (r == c) ? dcc : lrc;               // lanes r<c: garbage, unused
        #pragma unroll
        for (int c2 = c + 1; c2 < 32; ++c2) {
            const double lc2c = __shfl(A[c], c2, 32);   // L[c2][c]
            A[c2] = (r > c) ? fma(-A[c], lc2c, A[c2]) : A[c2];
        }
    }

    // ---- triangular inverse X = L^{-1} (f64); lane r accumulates row r in B ----
    double B[32];
    #pragma unroll
    for (int c = 0; c < 32; ++c) B[c] = (c == r) ? 1.0 : 0.0;
    #pragma unroll
    for (int j = 0; j < 32; ++j) {
        const double invdj = 1.0 / A[j];   // on lane j this is 1/L[j][j]
        #pragma unroll
        for (int c = 0; c <= j; ++c) {
            const double fin = B[c] * invdj;
            const double src = (r == j) ? fin : B[c];
            const double xjc = __shfl(src, j, 32);      // X[j][c]
            B[c] = (r == j) ? fin
                 : ((r > j) ? fma(-A[j], xjc, B[c]) : B[c]);
        }
    }
    // lane r: B[c] = X[r][c] for c<=r, exactly 0 for c>r.

    // ---- b = X * mu (f64), via shuffled mu ----
    const double mur = (double)mean_p[(size_t)pair * 32 + r];
    double bacc = 0.0;
    #pragma unroll
    for (int j = 0; j < 32; ++j)
        bacc += B[j] * __shfl(mur, j, 32);
    bOut[(size_t)pair * 32 + r] = (float)bacc;

    // ---- write Linv row r (f32, coalesced float4) ----
    {
        float4* lp = (float4*)(LinvOut + (size_t)pair * 1024 + r * 32);
        #pragma unroll
        for (int q = 0; q < 8; ++q)
            lp[q] = make_float4((float)B[4*q+0], (float)B[4*q+1],
                                (float)B[4*q+2], (float)B[4*q+3]);
    }

    // ---- c constant ----
    double lsd = log((double)ds_stds[dd * 32 + r]);
    #pragma unroll
    for (int off = 16; off >= 1; off >>= 1)
        lsd += __shfl_xor(lsd, off, 32);
    if (r == 0) {
        const float* mrow = mix + dd * 8;
        double mx = (double)mrow[0];
        #pragma unroll
        for (int q = 1; q < 8; ++q) mx = fmax(mx, (double)mrow[q]);
        double se = 0.0;
        #pragma unroll
        for (int q = 0; q < 8; ++q) se += exp((double)mrow[q] - mx);
        const double logpi = (double)mrow[k] - mx - log(se);
        const double LOG2PI = 1.8378770664093454836;  // log(2*pi)
        cOut[pair] = (float)(logpi - hld - 16.0 * LOG2PI - lsd);
    }
}

// Heavy kernel (f32): 512 blocks x 256 threads, one dd + 512 samples/block,
// 2 samples/thread. Linv[8][32][32] f32 in LDS (32 KB), broadcast reads.
__global__ __launch_bounds__(256) void gmm_main(
    const float* __restrict__ data,     // [1024,256,32]
    const float* __restrict__ ds_means, // [256,32]
    const float* __restrict__ ds_stds,  // [256,32]
    const float* __restrict__ Linv,     // [2048,32,32] f32
    const float* __restrict__ bvec,     // [2048,32] f32
    const float* __restrict__ cdk,      // [2048] f32
    float* __restrict__ out)            // [1024,256]
{
    const int dd = blockIdx.x;          // 0..255
    const int sc = blockIdx.y;          // 0..1
    const int t  = threadIdx.x;

    __shared__ float Ls[8192];          // 32 KB
    __shared__ float bs[256];
    __shared__ float cs[8];
    __shared__ float mn[32];
    __shared__ float is[32];

    {
        const float4* Lp = (const float4*)(Linv + (size_t)dd * 8192);
        float4* Ld = (float4*)Ls;
        for (int e = t; e < 2048; e += 256) Ld[e] = Lp[e];
    }
    bs[t] = bvec[(size_t)dd * 256 + t];
    if (t < 8)  cs[t] = cdk[dd * 8 + t];
    if (t < 32) { mn[t] = ds_means[dd*32+t]; is[t] = 1.0f / ds_stds[dd*32+t]; }
    __syncthreads();

    const int s0 = sc * 512 + t;
    const int s1 = s0 + 256;

    float y0[32], y1[32];
    {
        const float4* x0 = (const float4*)(data + ((size_t)s0 * 256 + dd) * 32);
        const float4* x1 = (const float4*)(data + ((size_t)s1 * 256 + dd) * 32);
        #pragma unroll
        for (int q = 0; q < 8; ++q) {
            const float4 va = x0[q];
            const float4 vb = x1[q];
            const int j4 = 4 * q;
            y0[j4+0] = (va.x - mn[j4+0]) * is[j4+0];
            y0[j4+1] = (va.y - mn[j4+1]) * is[j4+1];
            y0[j4+2] = (va.z - mn[j4+2]) * is[j4+2];
            y0[j4+3] = (va.w - mn[j4+3]) * is[j4+3];
            y1[j4+0] = (vb.x - mn[j4+0]) * is[j4+0];
            y1[j4+1] = (vb.y - mn[j4+1]) * is[j4+1];
            y1[j4+2] = (vb.z - mn[j4+2]) * is[j4+2];
            y1[j4+3] = (vb.w - mn[j4+3]) * is[j4+3];
        }
    }

    // online logsumexp state (no runtime-indexed arrays -> no scratch)
    float m0 = -1e30f, e0 = 0.f, m1 = -1e30f, e1 = 0.f;

    #pragma unroll 1
    for (int kk = 0; kk < 8; ++kk) {
        float q0 = 0.f, q1 = 0.f;
        #pragma unroll 1
        for (int i = 0; i < 32; i += 2) {
            const float* L0 = &Ls[(kk * 32 + i) * 32];
            const float* L1 = L0 + 32;
            const float b0 = bs[kk * 32 + i];
            const float b1 = bs[kk * 32 + i + 1];
            float z00a = -b0, z00b = 0.f;
            float z01a = -b1, z01b = 0.f;
            float z10a = -b0, z10b = 0.f;
            float z11a = -b1, z11b = 0.f;
            #pragma unroll
            for (int j = 0; j < 16; ++j) {
                const float l0 = L0[j], l1 = L1[j];
                z00a = fmaf(l0, y0[j], z00a);
                z01a = fmaf(l1, y0[j], z01a);
                z10a = fmaf(l0, y1[j], z10a);
                z11a = fmaf(l1, y1[j], z11a);
            }
            #pragma unroll
            for (int j = 16; j < 32; ++j) {
                const float l0 = L0[j], l1 = L1[j];
                z00b = fmaf(l0, y0[j], z00b);
                z01b = fmaf(l1, y0[j], z01b);
                z10b = fmaf(l0, y1[j], z10b);
                z11b = fmaf(l1, y1[j], z11b);
            }
            const float z00 = z00a + z00b;
            const float z01 = z01a + z01b;
            const float z10 = z10a + z10b;
            const float z11 = z11a + z11b;
            q0 = fmaf(z00, z00, q0);
            q0 = fmaf(z01, z01, q0);
            q1 = fmaf(z10, z10, q1);
            q1 = fmaf(z11, z11, q1);
        }
        const float a0 = cs[kk] - 0.5f * q0;
        const float a1 = cs[kk] - 0.5f * q1;
        const float nm0 = fmaxf(m0, a0);
        e0 = e0 * expf(m0 - nm0) + expf(a0 - nm0);
        m0 = nm0;
        const float nm1 = fmaxf(m1, a1);
        e1 = e1 * expf(m1 - nm1) + expf(a1 - nm1);
        m1 = nm1;
    }

    out[(size_t)s0 * 256 + dd] = m0 + logf(e0);
    out[(size_t)s1 * 256 + dd] = m1 + logf(e1);
}

extern "C" void kernel_launch(void* const* d_in, const int* in_sizes, int n_in,
                              void* d_out, int out_size, void* d_ws, size_t ws_size,
                              hipStream_t stream) {
    const float* data   = (const float*)d_in[0];   // [1024,256,32]
    const float* mix    = (const float*)d_in[1];   // [256,8]
    const float* mean_p = (const float*)d_in[2];   // [256,8,32]
    const float* cov_p  = (const float*)d_in[3];   // [256,8,32,32]
    const float* ds_m   = (const float*)d_in[4];   // [256,32]
    const float* ds_s   = (const float*)d_in[5];   // [256,32]
    float* out = (float*)d_out;

    float* Linv = (float*)d_ws;                 // 2048*1024 f32
    float* bvec = Linv + 2048 * 1024;           // 2048*32 f32
    float* cdk  = bvec + 2048 * 32;             // 2048 f32

    gmm_precompute<<<256, 256, 0, stream>>>(mix, mean_p, cov_p, ds_s,
                                            Linv, bvec, cdk);
    dim3 grid(256, 2);
    gmm_main<<<grid, 256, 0, stream>>>(data, ds_m, ds_s, Linv, bvec, cdk, out);
}

// Round 7
// 242.133 us; speedup vs baseline: 1.1320x; 1.1320x over previous
//
#include <hip/hip_runtime.h>
#include <math.h>

// GMM log-prob, S=1024 D=256 K=8 d=32. Target = dtype-faithful f32 numpy ref.
// cov is replicated BIT-EXACTLY in f32 per numpy's SSE3-baseline einsum
// (mul-round + 4-lane reversed add chains + hadd tree + f32 ridge) -- this is
// what makes the test pass; do not perturb that ordering.
//
// Precompute (one 32-lane half-wave per (d,k) pair), phase-separated to avoid
// the round-6 register spill (VGPR 256 + 2KB/thread scratch):
//   P1: cov rows + f64 Cholesky in REGISTERS (w[32]+A[32] ~ 96 VGPR live)
//   P2: L rows -> LDS (stride 33, 2-way = free), A dies
//   P3: inverse column-per-lane, x[32] only, broadcast LDS reads of L
//   P4: Linv f32 out from registers (row-coalesced); X->LDS; b row-dot; consts
// log-calls minimized via grouped products (f64 ~1e-15 deltas, invisible).
// ws layout (f32): Linv [2048*1024] | b [2048*32] | c [2048]  (~8.5 MB)

__global__ __launch_bounds__(128) void gmm_precompute(
    const float* __restrict__ mix,      // [256,8]
    const float* __restrict__ mean_p,   // [256,8,32]
    const float* __restrict__ cov_p,    // [256,8,32,32]
    const float* __restrict__ ds_stds,  // [256,32]
    float* __restrict__ LinvOut,        // [2048,32,32]
    float* __restrict__ bOut,           // [2048,32]
    float* __restrict__ cOut)           // [2048]
{
    const int tid  = threadIdx.x;
    const int sub  = tid >> 5;                 // 0..3 half-wave in block
    const int lane = tid & 31;                 // row (P1) / column (P3)
    const int pair = blockIdx.x * 4 + sub;     // 0..2047
    const int dd   = pair >> 3;
    const int k    = pair & 7;

    __shared__ double Lsh[4][32][33];          // [sub][row][col; 32=invDiag]

    // ---- P1a: load W row `lane` ----
    float w[32];
    {
        const float4* wp = (const float4*)(cov_p + (size_t)pair * 1024 + lane * 32);
        #pragma unroll
        for (int q = 0; q < 8; ++q) {
            const float4 v = wp[q];
            w[4*q+0] = v.x; w[4*q+1] = v.y; w[4*q+2] = v.z; w[4*q+3] = v.w;
        }
    }

    // ---- P1b: cov row in f32 (exact SSE3-emulated order) -> f64 A[] ----
    double A[32];
    #pragma unroll
    for (int c = 0; c < 32; ++c) {
        float p[32];
        #pragma unroll
        for (int j = 0; j < 32; ++j)
            p[j] = __fmul_rn(w[j], __shfl(w[j], c, 32));
        float acc[4];
        #pragma unroll
        for (int l = 0; l < 4; ++l) {
            float t1 = p[12+l];
            t1 = __fadd_rn(p[8+l], t1);
            t1 = __fadd_rn(p[4+l], t1);
            t1 = __fadd_rn(p[0+l], t1);
            float t2 = __fadd_rn(p[28+l], t1);
            t2 = __fadd_rn(p[24+l], t2);
            t2 = __fadd_rn(p[20+l], t2);
            acc[l] = __fadd_rn(p[16+l], t2);
        }
        float s = __fadd_rn(__fadd_rn(acc[0], acc[1]), __fadd_rn(acc[2], acc[3]));
        if (c == lane) s = __fadd_rn(s, 1.0e-5f);
        A[c] = (double)s;
    }

    // ---- P1c: Cholesky (f64) in registers; lane = row. Grouped logdet. ----
    double hld = 0.0, prod = 1.0, myInvD = 0.0;
    #pragma unroll
    for (int c = 0; c < 32; ++c) {
        const double dv  = __shfl(A[c], c, 32);    // updated C[c][c]
        const double dcc = sqrt(dv);
        prod *= dv;
        if ((c & 7) == 7) { hld += log(prod); prod = 1.0; }
        const double invd = 1.0 / dcc;
        if (lane == c) myInvD = invd;
        const double lrc = A[c] * invd;
        A[c] = (lane == c) ? dcc : lrc;            // lanes r<c keep garbage (unused)
        #pragma unroll
        for (int c2 = c + 1; c2 < 32; ++c2) {
            const double lc2c = __shfl(A[c], c2, 32);   // L[c2][c]
            A[c2] = (lane > c) ? fma(-A[c], lc2c, A[c2]) : A[c2];
        }
    }
    hld *= 0.5;   // dv = Lcc^2

    // ---- P2: stage L rows + invDiag in LDS; A dies here ----
    #pragma unroll
    for (int c = 0; c < 32; ++c) Lsh[sub][lane][c] = A[c];
    Lsh[sub][lane][32] = myInvD;
    __syncthreads();

    // ---- P3: forward substitution, lane = column of X = L^{-1} ----
    // x[rr] = (delta - sum_{j<rr} L[rr][j] x[j]) * invD[rr]; zeros emerge
    // naturally for rr < lane (lane-uniform code, broadcast reads).
    double x[32];
    #pragma unroll
    for (int rr = 0; rr < 32; ++rr) {
        double s = (rr == lane) ? 1.0 : 0.0;
        #pragma unroll
        for (int j = 0; j < rr; ++j)
            s = fma(-Lsh[sub][rr][j], x[j], s);
        x[rr] = s * Lsh[sub][rr][32];
    }
    __syncthreads();

    // ---- P4a: write Linv f32 (row-coalesced) and X -> LDS (row layout) ----
    #pragma unroll
    for (int rr = 0; rr < 32; ++rr) {
        Lsh[sub][rr][lane] = x[rr];
        LinvOut[(size_t)pair * 1024 + rr * 32 + lane] = (float)x[rr];
    }
    __syncthreads();

    // ---- P4b: b row `lane` = sum_j X[lane][j] * mu[j] (f64) ----
    const double mu_l = (double)mean_p[(size_t)pair * 32 + lane];
    double bacc = 0.0;
    #pragma unroll
    for (int j = 0; j < 32; ++j)
        bacc += Lsh[sub][lane][j] * __shfl(mu_l, j, 32);
    bOut[(size_t)pair * 32 + lane] = (float)bacc;

    // ---- P4c: c constant (product-butterfly for sum log std, 1 log) ----
    double sprod = (double)ds_stds[dd * 32 + lane];
    #pragma unroll
    for (int off = 16; off >= 1; off >>= 1)
        sprod *= __shfl_xor(sprod, off, 32);
    if (lane == 0) {
        const double lsd = log(sprod);
        const float* mrow = mix + dd * 8;
        double mx = (double)mrow[0];
        #pragma unroll
        for (int q = 1; q < 8; ++q) mx = fmax(mx, (double)mrow[q]);
        double se = 0.0;
        #pragma unroll
        for (int q = 0; q < 8; ++q) se += exp((double)mrow[q] - mx);
        const double logpi = (double)mrow[k] - mx - log(se);
        const double LOG2PI = 1.8378770664093454836;  // log(2*pi)
        cOut[pair] = (float)(logpi - hld - 16.0 * LOG2PI - lsd);
    }
}

// Heavy kernel (f32): 512 blocks x 256 threads, one dd + 512 samples/block,
// 2 samples/thread. Linv[8][32][32] f32 in LDS (32 KB), broadcast reads.
__global__ __launch_bounds__(256) void gmm_main(
    const float* __restrict__ data,     // [1024,256,32]
    const float* __restrict__ ds_means, // [256,32]
    const float* __restrict__ ds_stds,  // [256,32]
    const float* __restrict__ Linv,     // [2048,32,32] f32
    const float* __restrict__ bvec,     // [2048,32] f32
    const float* __restrict__ cdk,      // [2048] f32
    float* __restrict__ out)            // [1024,256]
{
    const int dd = blockIdx.x;          // 0..255
    const int sc = blockIdx.y;          // 0..1
    const int t  = threadIdx.x;

    __shared__ float Ls[8192];          // 32 KB
    __shared__ float bs[256];
    __shared__ float cs[8];
    __shared__ float mn[32];
    __shared__ float is[32];

    {
        const float4* Lp = (const float4*)(Linv + (size_t)dd * 8192);
        float4* Ld = (float4*)Ls;
        for (int e = t; e < 2048; e += 256) Ld[e] = Lp[e];
    }
    bs[t] = bvec[(size_t)dd * 256 + t];
    if (t < 8)  cs[t] = cdk[dd * 8 + t];
    if (t < 32) { mn[t] = ds_means[dd*32+t]; is[t] = 1.0f / ds_stds[dd*32+t]; }
    __syncthreads();

    const int s0 = sc * 512 + t;
    const int s1 = s0 + 256;

    float y0[32], y1[32];
    {
        const float4* x0 = (const float4*)(data + ((size_t)s0 * 256 + dd) * 32);
        const float4* x1 = (const float4*)(data + ((size_t)s1 * 256 + dd) * 32);
        #pragma unroll
        for (int q = 0; q < 8; ++q) {
            const float4 va = x0[q];
            const float4 vb = x1[q];
            const int j4 = 4 * q;
            y0[j4+0] = (va.x - mn[j4+0]) * is[j4+0];
            y0[j4+1] = (va.y - mn[j4+1]) * is[j4+1];
            y0[j4+2] = (va.z - mn[j4+2]) * is[j4+2];
            y0[j4+3] = (va.w - mn[j4+3]) * is[j4+3];
            y1[j4+0] = (vb.x - mn[j4+0]) * is[j4+0];
            y1[j4+1] = (vb.y - mn[j4+1]) * is[j4+1];
            y1[j4+2] = (vb.z - mn[j4+2]) * is[j4+2];
            y1[j4+3] = (vb.w - mn[j4+3]) * is[j4+3];
        }
    }

    // online logsumexp state (no runtime-indexed arrays -> no scratch)
    float m0 = -1e30f, e0 = 0.f, m1 = -1e30f, e1 = 0.f;

    #pragma unroll 1
    for (int kk = 0; kk < 8; ++kk) {
        float q0 = 0.f, q1 = 0.f;
        #pragma unroll 1
        for (int i = 0; i < 32; i += 2) {
            const float* L0 = &Ls[(kk * 32 + i) * 32];
            const float* L1 = L0 + 32;
            const float b0 = bs[kk * 32 + i];
            const float b1 = bs[kk * 32 + i + 1];
            float z00a = -b0, z00b = 0.f;
            float z01a = -b1, z01b = 0.f;
            float z10a = -b0, z10b = 0.f;
            float z11a = -b1, z11b = 0.f;
            #pragma unroll
            for (int j = 0; j < 16; ++j) {
                const float l0 = L0[j], l1 = L1[j];
                z00a = fmaf(l0, y0[j], z00a);
                z01a = fmaf(l1, y0[j], z01a);
                z10a = fmaf(l0, y1[j], z10a);
                z11a = fmaf(l1, y1[j], z11a);
            }
            #pragma unroll
            for (int j = 16; j < 32; ++j) {
                const float l0 = L0[j], l1 = L1[j];
                z00b = fmaf(l0, y0[j], z00b);
                z01b = fmaf(l1, y0[j], z01b);
                z10b = fmaf(l0, y1[j], z10b);
                z11b = fmaf(l1, y1[j], z11b);
            }
            const float z00 = z00a + z00b;
            const float z01 = z01a + z01b;
            const float z10 = z10a + z10b;
            const float z11 = z11a + z11b;
            q0 = fmaf(z00, z00, q0);
            q0 = fmaf(z01, z01, q0);
            q1 = fmaf(z10, z10, q1);
            q1 = fmaf(z11, z11, q1);
        }
        const float a0 = cs[kk] - 0.5f * q0;
        const float a1 = cs[kk] - 0.5f * q1;
        const float nm0 = fmaxf(m0, a0);
        e0 = e0 * expf(m0 - nm0) + expf(a0 - nm0);
        m0 = nm0;
        const float nm1 = fmaxf(m1, a1);
        e1 = e1 * expf(m1 - nm1) + expf(a1 - nm1);
        m1 = nm1;
    }

    out[(size_t)s0 * 256 + dd] = m0 + logf(e0);
    out[(size_t)s1 * 256 + dd] = m1 + logf(e1);
}

extern "C" void kernel_launch(void* const* d_in, const int* in_sizes, int n_in,
                              void* d_out, int out_size, void* d_ws, size_t ws_size,
                              hipStream_t stream) {
    const float* data   = (const float*)d_in[0];   // [1024,256,32]
    const float* mix    = (const float*)d_in[1];   // [256,8]
    const float* mean_p = (const float*)d_in[2];   // [256,8,32]
    const float* cov_p  = (const float*)d_in[3];   // [256,8,32,32]
    const float* ds_m   = (const float*)d_in[4];   // [256,32]
    const float* ds_s   = (const float*)d_in[5];   // [256,32]
    float* out = (float*)d_out;

    float* Linv = (float*)d_ws;                 // 2048*1024 f32
    float* bvec = Linv + 2048 * 1024;           // 2048*32 f32
    float* cdk  = bvec + 2048 * 32;             // 2048 f32

    gmm_precompute<<<512, 128, 0, stream>>>(mix, mean_p, cov_p, ds_s,
                                            Linv, bvec, cdk);
    dim3 grid(256, 2);
    gmm_main<<<grid, 256, 0, stream>>>(data, ds_m, ds_s, Linv, bvec, cdk, out);
}

// Round 8
// 143.182 us; speedup vs baseline: 1.9144x; 1.6911x over previous
//
#include <hip/hip_runtime.h>
#include <math.h>

// GMM log-prob, S=1024 D=256 K=8 d=32. Target = dtype-faithful f32 numpy ref.
// cov is replicated BIT-EXACTLY in f32 per numpy's SSE3-baseline einsum
// (mul-round + 4-lane reversed add chains + hadd tree + f32 ridge) -- this is
// what makes the test pass; do not perturb that ordering.
//
// Precompute: one 32-lane half-wave per (d,k) pair; working matrices in LDS
// (stride-33 f64 padding -> worst case 2-way bank aliasing = free); ALL loops
// runtime (#pragma unroll 1) so register arrays are just w[32]/p[32] f32.
// This kills the round-6/7 spill (VGPR 256, 2KB/thread scratch, 137MB WRITE).
// No barriers: each pair is wave-internal lockstep.
// f64 op ORDER kept identical to the passing round-7 code -> same bits.
// ws layout (f32): Linv [2048*1024] | b [2048*32] | c [2048]  (~8.5 MB)

__global__ __launch_bounds__(128) void gmm_precompute(
    const float* __restrict__ mix,      // [256,8]
    const float* __restrict__ mean_p,   // [256,8,32]
    const float* __restrict__ cov_p,    // [256,8,32,32]
    const float* __restrict__ ds_stds,  // [256,32]
    float* __restrict__ LinvOut,        // [2048,32,32]
    float* __restrict__ bOut,           // [2048,32]
    float* __restrict__ cOut)           // [2048]
{
    const int tid  = threadIdx.x;
    const int sub  = tid >> 5;                 // 0..3 half-wave in block
    const int lane = tid & 31;
    const int pair = blockIdx.x * 4 + sub;     // 0..2047
    const int dd   = pair >> 3;
    const int k    = pair & 7;

    __shared__ double Csh[4][32][33];          // [sub][row][col]; col32 = invD
    __shared__ double Xsh[4][32][33];          // X = L^{-1}
    double (*C)[33] = Csh[sub];
    double (*X)[33] = Xsh[sub];

    // ---- P1: load W row `lane` (registers) ----
    float w[32];
    {
        const float4* wp = (const float4*)(cov_p + (size_t)pair * 1024 + lane * 32);
        #pragma unroll
        for (int q = 0; q < 8; ++q) {
            const float4 v = wp[q];
            w[4*q+0] = v.x; w[4*q+1] = v.y; w[4*q+2] = v.z; w[4*q+3] = v.w;
        }
    }

    // ---- P2: cov row in f32 (exact SSE3-emulated order) -> LDS f64 ----
    #pragma unroll 1
    for (int c = 0; c < 32; ++c) {
        float p[32];
        #pragma unroll
        for (int j = 0; j < 32; ++j)
            p[j] = __fmul_rn(w[j], __shfl(w[j], c, 32));
        float acc[4];
        #pragma unroll
        for (int l = 0; l < 4; ++l) {
            float t1 = p[12+l];
            t1 = __fadd_rn(p[8+l], t1);
            t1 = __fadd_rn(p[4+l], t1);
            t1 = __fadd_rn(p[0+l], t1);
            float t2 = __fadd_rn(p[28+l], t1);
            t2 = __fadd_rn(p[24+l], t2);
            t2 = __fadd_rn(p[20+l], t2);
            acc[l] = __fadd_rn(p[16+l], t2);
        }
        float s = __fadd_rn(__fadd_rn(acc[0], acc[1]), __fadd_rn(acc[2], acc[3]));
        if (c == lane) s = __fadd_rn(s, 1.0e-5f);
        C[lane][c] = (double)s;
    }

    // ---- P3: Cholesky (f64) in LDS; lane r owns row r. Grouped logdet. ----
    double hld = 0.0, prod = 1.0;
    #pragma unroll 1
    for (int c = 0; c < 32; ++c) {
        const double dv  = C[c][c];            // broadcast read
        const double dcc = sqrt(dv);
        prod *= dv;
        if ((c & 7) == 7) { hld += log(prod); prod = 1.0; }
        const double invd = 1.0 / dcc;
        double lrc = 0.0;
        if (lane > c) {
            lrc = C[lane][c] * invd;
            C[lane][c] = lrc;                  // L[lane][c]
        } else if (lane == c) {
            C[c][c]  = dcc;
            C[c][32] = invd;                   // stash 1/L[c][c]
        }
        if (lane > c) {
            #pragma unroll 1
            for (int c2 = c + 1; c2 <= lane; ++c2)
                C[lane][c2] = fma(-lrc, C[c2][c], C[lane][c2]);
        }
    }
    hld *= 0.5;   // dv = Lcc^2

    // ---- P4: forward substitution; lane = column of X = L^{-1} ----
    // Identical op order to round 7: s = fma(-L[rr][j], X[j][col], s), j asc,
    // then * invD[rr]. Zeros for rr < col emerge exactly.
    #pragma unroll 1
    for (int rr = 0; rr < 32; ++rr) {
        double s = (rr == lane) ? 1.0 : 0.0;
        #pragma unroll 1
        for (int j = 0; j < rr; ++j)
            s = fma(-C[rr][j], X[j][lane], s);  // C[rr][j] broadcast; X own col
        X[rr][lane] = s * C[rr][32];
    }

    // ---- P5a: write Linv f32 (coalesced: lanes span a row) ----
    #pragma unroll 1
    for (int rr = 0; rr < 32; ++rr)
        LinvOut[(size_t)pair * 1024 + rr * 32 + lane] = (float)X[rr][lane];

    // ---- P5b: b row `lane` = sum_j X[lane][j] * mu[j] (f64, asc j) ----
    const double mu_l = (double)mean_p[(size_t)pair * 32 + lane];
    double bacc = 0.0;
    #pragma unroll 1
    for (int j = 0; j < 32; ++j)
        bacc += X[lane][j] * __shfl(mu_l, j, 32);
    bOut[(size_t)pair * 32 + lane] = (float)bacc;

    // ---- P5c: c constant (product-butterfly for sum log std, 1 log) ----
    double sprod = (double)ds_stds[dd * 32 + lane];
    #pragma unroll
    for (int off = 16; off >= 1; off >>= 1)
        sprod *= __shfl_xor(sprod, off, 32);
    if (lane == 0) {
        const double lsd = log(sprod);
        const float* mrow = mix + dd * 8;
        double mx = (double)mrow[0];
        #pragma unroll
        for (int q = 1; q < 8; ++q) mx = fmax(mx, (double)mrow[q]);
        double se = 0.0;
        #pragma unroll
        for (int q = 0; q < 8; ++q) se += exp((double)mrow[q] - mx);
        const double logpi = (double)mrow[k] - mx - log(se);
        const double LOG2PI = 1.8378770664093454836;  // log(2*pi)
        cOut[pair] = (float)(logpi - hld - 16.0 * LOG2PI - lsd);
    }
}

// Heavy kernel (f32): 512 blocks x 256 threads, one dd + 512 samples/block,
// 2 samples/thread. Linv[8][32][32] f32 in LDS (32 KB), broadcast reads.
__global__ __launch_bounds__(256) void gmm_main(
    const float* __restrict__ data,     // [1024,256,32]
    const float* __restrict__ ds_means, // [256,32]
    const float* __restrict__ ds_stds,  // [256,32]
    const float* __restrict__ Linv,     // [2048,32,32] f32
    const float* __restrict__ bvec,     // [2048,32] f32
    const float* __restrict__ cdk,      // [2048] f32
    float* __restrict__ out)            // [1024,256]
{
    const int dd = blockIdx.x;          // 0..255
    const int sc = blockIdx.y;          // 0..1
    const int t  = threadIdx.x;

    __shared__ float Ls[8192];          // 32 KB
    __shared__ float bs[256];
    __shared__ float cs[8];
    __shared__ float mn[32];
    __shared__ float is[32];

    {
        const float4* Lp = (const float4*)(Linv + (size_t)dd * 8192);
        float4* Ld = (float4*)Ls;
        for (int e = t; e < 2048; e += 256) Ld[e] = Lp[e];
    }
    bs[t] = bvec[(size_t)dd * 256 + t];
    if (t < 8)  cs[t] = cdk[dd * 8 + t];
    if (t < 32) { mn[t] = ds_means[dd*32+t]; is[t] = 1.0f / ds_stds[dd*32+t]; }
    __syncthreads();

    const int s0 = sc * 512 + t;
    const int s1 = s0 + 256;

    float y0[32], y1[32];
    {
        const float4* x0 = (const float4*)(data + ((size_t)s0 * 256 + dd) * 32);
        const float4* x1 = (const float4*)(data + ((size_t)s1 * 256 + dd) * 32);
        #pragma unroll
        for (int q = 0; q < 8; ++q) {
            const float4 va = x0[q];
            const float4 vb = x1[q];
            const int j4 = 4 * q;
            y0[j4+0] = (va.x - mn[j4+0]) * is[j4+0];
            y0[j4+1] = (va.y - mn[j4+1]) * is[j4+1];
            y0[j4+2] = (va.z - mn[j4+2]) * is[j4+2];
            y0[j4+3] = (va.w - mn[j4+3]) * is[j4+3];
            y1[j4+0] = (vb.x - mn[j4+0]) * is[j4+0];
            y1[j4+1] = (vb.y - mn[j4+1]) * is[j4+1];
            y1[j4+2] = (vb.z - mn[j4+2]) * is[j4+2];
            y1[j4+3] = (vb.w - mn[j4+3]) * is[j4+3];
        }
    }

    // online logsumexp state (no runtime-indexed arrays -> no scratch)
    float m0 = -1e30f, e0 = 0.f, m1 = -1e30f, e1 = 0.f;

    #pragma unroll 1
    for (int kk = 0; kk < 8; ++kk) {
        float q0 = 0.f, q1 = 0.f;
        #pragma unroll 1
        for (int i = 0; i < 32; i += 2) {
            const float* L0 = &Ls[(kk * 32 + i) * 32];
            const float* L1 = L0 + 32;
            const float b0 = bs[kk * 32 + i];
            const float b1 = bs[kk * 32 + i + 1];
            float z00a = -b0, z00b = 0.f;
            float z01a = -b1, z01b = 0.f;
            float z10a = -b0, z10b = 0.f;
            float z11a = -b1, z11b = 0.f;
            #pragma unroll
            for (int j = 0; j < 16; ++j) {
                const float l0 = L0[j], l1 = L1[j];
                z00a = fmaf(l0, y0[j], z00a);
                z01a = fmaf(l1, y0[j], z01a);
                z10a = fmaf(l0, y1[j], z10a);
                z11a = fmaf(l1, y1[j], z11a);
            }
            #pragma unroll
            for (int j = 16; j < 32; ++j) {
                const float l0 = L0[j], l1 = L1[j];
                z00b = fmaf(l0, y0[j], z00b);
                z01b = fmaf(l1, y0[j], z01b);
                z10b = fmaf(l0, y1[j], z10b);
                z11b = fmaf(l1, y1[j], z11b);
            }
            const float z00 = z00a + z00b;
            const float z01 = z01a + z01b;
            const float z10 = z10a + z10b;
            const float z11 = z11a + z11b;
            q0 = fmaf(z00, z00, q0);
            q0 = fmaf(z01, z01, q0);
            q1 = fmaf(z10, z10, q1);
            q1 = fmaf(z11, z11, q1);
        }
        const float a0 = cs[kk] - 0.5f * q0;
        const float a1 = cs[kk] - 0.5f * q1;
        const float nm0 = fmaxf(m0, a0);
        e0 = e0 * expf(m0 - nm0) + expf(a0 - nm0);
        m0 = nm0;
        const float nm1 = fmaxf(m1, a1);
        e1 = e1 * expf(m1 - nm1) + expf(a1 - nm1);
        m1 = nm1;
    }

    out[(size_t)s0 * 256 + dd] = m0 + logf(e0);
    out[(size_t)s1 * 256 + dd] = m1 + logf(e1);
}

extern "C" void kernel_launch(void* const* d_in, const int* in_sizes, int n_in,
                              void* d_out, int out_size, void* d_ws, size_t ws_size,
                              hipStream_t stream) {
    const float* data   = (const float*)d_in[0];   // [1024,256,32]
    const float* mix    = (const float*)d_in[1];   // [256,8]
    const float* mean_p = (const float*)d_in[2];   // [256,8,32]
    const float* cov_p  = (const float*)d_in[3];   // [256,8,32,32]
    const float* ds_m   = (const float*)d_in[4];   // [256,32]
    const float* ds_s   = (const float*)d_in[5];   // [256,32]
    float* out = (float*)d_out;

    float* Linv = (float*)d_ws;                 // 2048*1024 f32
    float* bvec = Linv + 2048 * 1024;           // 2048*32 f32
    float* cdk  = bvec + 2048 * 32;             // 2048 f32

    gmm_precompute<<<512, 128, 0, stream>>>(mix, mean_p, cov_p, ds_s,
                                            Linv, bvec, cdk);
    dim3 grid(256, 2);
    gmm_main<<<grid, 256, 0, stream>>>(data, ds_m, ds_s, Linv, bvec, cdk, out);
}